// Round 18
// baseline (20.450 us; speedup 1.0000x reference)
//
#include <hip/hip_runtime.h>
#include <hip/hip_bf16.h>

#define C_IN  32
#define C_OUT 64
#define HH    64
#define WW    64

typedef __attribute__((ext_vector_type(4))) short short4v;
typedef __attribute__((ext_vector_type(4))) float f32x4;

static __device__ __forceinline__ unsigned short f2bf(float f) {
    unsigned u = __builtin_bit_cast(unsigned, f);
    unsigned r = (u + 0x7FFFu + ((u >> 16) & 1u)) >> 16;   // RNE
    return (unsigned short)r;
}
static __device__ __forceinline__ float bf2f(unsigned short b) {
    unsigned u = ((unsigned)b) << 16;
    return __builtin_bit_cast(float, u);
}

#if defined(__has_builtin)
#  if __has_builtin(__builtin_amdgcn_mfma_f32_16x16x16bf16_1k)
#    define HAVE_MFMA16_BUILTIN 1
#  endif
#endif

static __device__ __forceinline__ f32x4 mfma16(short4v a, short4v b, f32x4 c) {
#ifdef HAVE_MFMA16_BUILTIN
    return __builtin_amdgcn_mfma_f32_16x16x16bf16_1k(a, b, c, 0, 0, 0);
#else
    asm("v_mfma_f32_16x16x16_bf16 %0, %1, %2, %0" : "+v"(c) : "v"(a), "v"(b));
    return c;
#endif
}

// ---------------------------------------------------------------------------
// FUSED W~ pack, K=16 hi-only edition. Thread tid (0..511):
//   ihp = tid>>8 (ic half), oct = (tid>>6)&3, lane = tid&63,
//   oc = oct*16 + (lane&15), ic0 = ihp*16 + (lane>>4)*4  (4 ics/thread).
// W~_k = Ew(k) * (w_k if (P+k) odd), Ew(k) = prod_{j>=k, (P+j) even} w_j
// (identical math to r15-r17). LDS layout (K=16 frag, verified r9):
//   B16[ihp*2304 + (k*4 + oct)*64 + lane] = short4 {4 ics' bf16 hi}  (8B)
// Per half 18KB; both halves 36KB.
// ---------------------------------------------------------------------------
template<int P>
__device__ __forceinline__ void packB(const float* __restrict__ w,
                                      short4v* __restrict__ B16, int tid)
{
    int ihp  = tid >> 8;
    int oct  = (tid >> 6) & 3;
    int lane = tid & 63;
    int oc   = oct * 16 + (lane & 15);
    int ic0  = ihp * 16 + ((lane >> 4) << 2);

    // 36 consecutive floats = 4 ic-rows x 9 taps; byte base (oc*32+ic0)*9*4
    // is a multiple of 144 -> 16B-aligned: 9 dwordx4 loads.
    float wv[36];
    const f32x4* src = (const f32x4*)(w + ((size_t)oc * C_IN + ic0) * 9);
    #pragma unroll
    for (int i = 0; i < 9; ++i) {
        f32x4 v = src[i];
        wv[4 * i + 0] = v.x; wv[4 * i + 1] = v.y;
        wv[4 * i + 2] = v.z; wv[4 * i + 3] = v.w;
    }

    // Suffix products in place (identical math to r15-r17).
    #pragma unroll
    for (int a = 0; a < 4; ++a) {
        float Ew = 1.f;
        #pragma unroll
        for (int k = 8; k >= 0; --k) {
            float wk = wv[9 * a + k];
            if (((P + k) & 1) == 0) { Ew *= wk; wv[9 * a + k] = Ew; }
            else                    { wv[9 * a + k] = wk * Ew; }
        }
    }

    // Assemble + write: 9k x hi-only ds_write_b64.
    #pragma unroll
    for (int k = 0; k < 9; ++k) {
        short4v vh;
        #pragma unroll
        for (int a = 0; a < 4; ++a)
            vh[a] = (short)f2bf(wv[9 * a + k]);
        B16[ihp * 2304 + (k * 4 + oct) * 64 + lane] = vh;
    }
}

// ---------------------------------------------------------------------------
// GEMM body — K=16, 2-term: C_half = X*Wh (Xh*Wh + Xl*Wh; products exact in
// MFMA, so this is exactly X*round_bf16(W~)). A-frag mapping (verified r9):
// lane row = l&15, K-elems icl = (l>>4)*4 + j. C mapping as K=32 (m89).
// 72 MFMA/wave (9k x 4oct x 2 terms).
// ---------------------------------------------------------------------------
template<int P>
__device__ __forceinline__ void aeg_gemm(
    float (&xt)[4][9], const short4v* __restrict__ Bq, f32x4 (&acc)[4], int l)
{
    // X~: suffix products of odd-step x's; even steps multiply own x.
    #pragma unroll
    for (int a = 0; a < 4; ++a) {
        float Ox = 1.f;
        #pragma unroll
        for (int k = 8; k >= 0; --k) {
            if (((P + k) & 1) == 1) { Ox *= xt[a][k]; xt[a][k] = Ox; }
            else                    { xt[a][k] = xt[a][k] * Ox; }
        }
    }

    #pragma unroll
    for (int t = 0; t < 4; ++t) acc[t] = (f32x4){0.f, 0.f, 0.f, 0.f};

    #pragma unroll
    for (int k = 0; k < 9; ++k) {
        short4v ah, al;
        #pragma unroll
        for (int a = 0; a < 4; ++a) {
            float v  = xt[a][k];
            __hip_bfloat16 bh = __float2bfloat16(v);          // RNE
            float fh = __bfloat162float(bh);
            __hip_bfloat16 bl = __float2bfloat16(v - fh);
            ah[a] = (short)__builtin_bit_cast(unsigned short, bh);
            al[a] = (short)__builtin_bit_cast(unsigned short, bl);
        }
        #pragma unroll
        for (int t = 0; t < 4; ++t) {
            short4v bh = Bq[(k * 4 + t) * 64 + l];             // W~ hi only
            acc[t] = mfma16(ah, bh, acc[t]);
            acc[t] = mfma16(al, bh, acc[t]);
        }
    }
#ifndef HAVE_MFMA16_BUILTIN
    asm volatile("s_nop 7\n\ts_nop 7" ::: );  // MFMA->VALU read hazard guard
#endif
}

// ---------------------------------------------------------------------------
// Main kernel: block = 1 n x 2 rows x 64 cols x ONE parity, 512 thr = 8
// waves. Waves 0-3: ic 0-15; waves 4-7: ic 16-31 (ic-split duplicates NO
// work — suffix products are per-ic). Grid 512 -> 2 blocks/CU -> 4 waves/
// SIMD (2x TLP vs r17), every per-thread serial chain halved.
// ic-halves combined in LDS (no atomics/memset); coalesced epilogue (r14).
// ---------------------------------------------------------------------------
__global__ __launch_bounds__(512, 4) void aeg_mfma(
    const float* __restrict__ x, const float* __restrict__ w,
    float* __restrict__ out)
{
    __shared__ __attribute__((aligned(16))) unsigned short Blds[18432]; // 36KB

    int bid = blockIdx.x;
    int pp  = bid & 1;           // parity (0..1)
    int br  = (bid >> 1) & 31;   // row-block (0..31), 2 rows each
    int n   = bid >> 6;          // batch (0..7)
    int i0  = br * 2;
    int tid = threadIdx.x;

    if (pp == 0) packB<0>(w, (short4v*)Blds, tid);
    else         packB<1>(w, (short4v*)Blds, tid);
    __syncthreads();

    int wvv = __builtin_amdgcn_readfirstlane(tid >> 6);  // wave 0..7
    int ih  = wvv >> 2;          // ic half (0..1)
    int grp = wvv & 3;           // M-group 0..3
    int l   = tid & 63;

    int qA = grp * 16 + (l & 15);
    int iA = i0 + (qA >> 5);
    int jA = 2 * (qA & 31) + ((iA + pp) & 1);
    int icb = ih * 16 + ((l >> 4) << 2);

    float xt[4][9];
    #pragma unroll
    for (int a = 0; a < 4; ++a) {
        const float* xb = x + ((size_t)n * C_IN + icb + a) * (HH * WW);
        #pragma unroll
        for (int di = 0; di < 3; ++di) {
            int ii = iA + di - 1;
            #pragma unroll
            for (int dj = 0; dj < 3; ++dj) {
                int jj = jA + dj - 1;
                bool ok = ((unsigned)ii < 64u) && ((unsigned)jj < 64u);
                xt[a][di * 3 + dj] = ok ? xb[ii * WW + jj] : 0.f;
            }
        }
    }

    const short4v* Bq = (const short4v*)Blds + ih * 2304;
    f32x4 acc[4];
    if (pp == 0) aeg_gemm<0>(xt, Bq, acc, l);
    else         aeg_gemm<1>(xt, Bq, acc, l);

    // ---- Epilogue: combine ic-halves in LDS, then coalesced store ----
    __syncthreads();                       // all B reads done; Blds reusable
    float* cls = (float*)Blds;             // C-tile: cls[oc*65 + q], 16.6KB

    int colc = l & 15;
    int rgrp = l >> 4;
    if (ih == 0) {
        #pragma unroll
        for (int t = 0; t < 4; ++t) {
            int oc = t * 16 + colc;
            #pragma unroll
            for (int r = 0; r < 4; ++r) {
                int q = grp * 16 + rgrp * 4 + r;
                cls[oc * 65 + q] = acc[t][r];
            }
        }
    }
    __syncthreads();
    if (ih == 1) {
        #pragma unroll
        for (int t = 0; t < 4; ++t) {
            int oc = t * 16 + colc;
            #pragma unroll
            for (int r = 0; r < 4; ++r) {
                int q = grp * 16 + rgrp * 4 + r;
                cls[oc * 65 + q] += acc[t][r];
            }
        }
    }
    __syncthreads();

    // Structured write-out: lane -> q, 64 lanes = one oc's 2-row stripe.
    #pragma unroll
    for (int v = 0; v < 8; ++v) {
        int flat = v * 512 + tid;          // 0..4095
        int oc   = flat >> 6;
        int q    = flat & 63;
        int i    = i0 + (q >> 5);
        int j    = 2 * (q & 31) + ((i + pp) & 1);
        out[(((size_t)n * C_OUT + oc) * HH + i) * WW + j] = cls[oc * 65 + q];
    }
}

extern "C" void kernel_launch(void* const* d_in, const int* in_sizes, int n_in,
                              void* d_out, int out_size, void* d_ws, size_t ws_size,
                              hipStream_t stream) {
    const float* x = (const float*)d_in[0];
    const float* w = (const float*)d_in[1];
    float* out = (float*)d_out;
    (void)d_ws; (void)ws_size;

    aeg_mfma<<<512, 512, 0, stream>>>(x, w, out);
}

// Round 19
// 18.619 us; speedup vs baseline: 1.0983x; 1.0983x over previous
//
#include <hip/hip_runtime.h>
#include <hip/hip_bf16.h>

#define C_IN  32
#define C_OUT 64
#define HH    64
#define WW    64

typedef __attribute__((ext_vector_type(8))) short short8v;
typedef __attribute__((ext_vector_type(4))) float f32x4;

static __device__ __forceinline__ unsigned short f2bf(float f) {
    unsigned u = __builtin_bit_cast(unsigned, f);
    unsigned r = (u + 0x7FFFu + ((u >> 16) & 1u)) >> 16;   // RNE
    return (unsigned short)r;
}
static __device__ __forceinline__ float bf2f(unsigned short b) {
    unsigned u = ((unsigned)b) << 16;
    return __builtin_bit_cast(float, u);
}

// x LDS geometry: per ic: [row:4][par:2][slot:34], slot = h+1 (h = col>>1),
// slot0/par1 = col -1 halo, slot33/par0 = col 64 halo (zeroed).
// Per-ic stride 273 = 4*68+1 (== 1 mod 4 -> ic-groups of 8 land on bank
// offsets {0,8,16,24}; 16-lane stride-1 reads -> <=2-way alias = free).
#define XS_IC   273
#define XS_ROW  68
#define XS_PAR  34

// ---------------------------------------------------------------------------
// FUSED W~ pack (r17 structure, hi-only, UNCHANGED).
// Thread = (oct = tid>>6, lane = tid&63): oc = oct*16 + (lane&15),
// ic = (lane>>4)*8 .. +7.  W~_k = Ew(k)*(w_k if (P+k) odd),
// Ew(k) = prod_{j>=k,(P+j) even} w_j.
// LDS: B16[(k*4 + oct)*64 + lane] = short8 {8 ics' bf16 hi}  (16B)
// ---------------------------------------------------------------------------
template<int P>
__device__ __forceinline__ void packB(const float* __restrict__ w,
                                      short8v* __restrict__ B16, int tid)
{
    int oct  = tid >> 6;
    int lane = tid & 63;
    int oc   = oct * 16 + (lane & 15);
    int icb  = (lane >> 4) * 8;

    float wv[72];
    const f32x4* src = (const f32x4*)(w + ((size_t)oc * C_IN + icb) * 9);
    #pragma unroll
    for (int i = 0; i < 18; ++i) {
        f32x4 v = src[i];
        wv[4 * i + 0] = v.x; wv[4 * i + 1] = v.y;
        wv[4 * i + 2] = v.z; wv[4 * i + 3] = v.w;
    }

    #pragma unroll
    for (int a = 0; a < 8; ++a) {
        float Ew = 1.f;
        #pragma unroll
        for (int k = 8; k >= 0; --k) {
            float wk = wv[9 * a + k];
            if (((P + k) & 1) == 0) { Ew *= wk; wv[9 * a + k] = Ew; }
            else                    { wv[9 * a + k] = wk * Ew; }
        }
    }

    #pragma unroll
    for (int k = 0; k < 9; ++k) {
        short8v vh;
        #pragma unroll
        for (int a = 0; a < 8; ++a)
            vh[a] = (short)f2bf(wv[9 * a + k]);
        B16[(k * 4 + oct) * 64 + lane] = vh;
    }
}

// ---------------------------------------------------------------------------
// GEMM body — r17 verified (A = X~, B = W~ hi, 2-term). UNCHANGED.
// C mapping (m89): row=(l>>4)*4+r -> position, col=l&15 -> oc.
// ---------------------------------------------------------------------------
template<int P>
__device__ __forceinline__ void aeg_gemm(
    float (&xt)[8][9], const short8v* __restrict__ Bq, f32x4 (&acc)[4], int l)
{
    #pragma unroll
    for (int a = 0; a < 8; ++a) {
        float Ox = 1.f;
        #pragma unroll
        for (int k = 8; k >= 0; --k) {
            if (((P + k) & 1) == 1) { Ox *= xt[a][k]; xt[a][k] = Ox; }
            else                    { xt[a][k] = xt[a][k] * Ox; }
        }
    }

    #pragma unroll
    for (int t = 0; t < 4; ++t) acc[t] = (f32x4){0.f, 0.f, 0.f, 0.f};

    #pragma unroll
    for (int k = 0; k < 9; ++k) {
        short8v ah, al;
        #pragma unroll
        for (int a = 0; a < 8; ++a) {
            float v  = xt[a][k];
            __hip_bfloat16 bh = __float2bfloat16(v);          // RNE
            float fh = __bfloat162float(bh);
            __hip_bfloat16 bl = __float2bfloat16(v - fh);
            ah[a] = (short)__builtin_bit_cast(unsigned short, bh);
            al[a] = (short)__builtin_bit_cast(unsigned short, bl);
        }
        #pragma unroll
        for (int t = 0; t < 4; ++t) {
            short8v bh = Bq[(k * 4 + t) * 64 + l];             // W~ hi only
            acc[t] = __builtin_amdgcn_mfma_f32_16x16x32_bf16(ah, bh, acc[t], 0, 0, 0);
            acc[t] = __builtin_amdgcn_mfma_f32_16x16x32_bf16(al, bh, acc[t], 0, 0, 0);
        }
    }
}

// ---------------------------------------------------------------------------
// Main kernel: block = 1 n x 2 rows x 64 cols x ONE parity, 256 thr = 4
// waves (r17 base). NEW: x-slab (32ic x 4rows x 64cols) staged via 8 fully
// coalesced dwordx4/thread into parity-split LDS; tap loads become pipelined
// LDS reads (no per-batch global-latency waits, no boundary masks).
// B pack, GEMM, coalesced epilogue unchanged from r17 (19.8us, passed).
// ---------------------------------------------------------------------------
__global__ __launch_bounds__(256, 2) void aeg_mfma(
    const float* __restrict__ x, const float* __restrict__ w,
    float* __restrict__ out)
{
    __shared__ __attribute__((aligned(16))) unsigned short Blds[18432]; // 36KB
    __shared__ float xs[C_IN * XS_IC];                                  // 34.9KB

    int bid = blockIdx.x;
    int pp  = bid & 1;           // parity (0..1)
    int br  = (bid >> 1) & 31;   // row-block (0..31), 2 rows each
    int n   = bid >> 6;          // batch (0..7)
    int i0  = br * 2;
    int tid = threadIdx.x;

    // ---- Stage x slab: rows i0-1..i0+2, cols 0..63, all 32 ic ----
    // 2048 vec4 chunks, 8/thread, fully coalesced; parity-split scatter.
    {
        const float* xn = x + (size_t)n * C_IN * HH * WW;
        #pragma unroll
        for (int c8 = 0; c8 < 8; ++c8) {
            int chunk = c8 * 256 + tid;      // 0..2047
            int ic  = chunk >> 6;
            int row = (chunk >> 4) & 3;
            int cv  = chunk & 15;
            int ii  = i0 - 1 + row;
            f32x4 v = (f32x4){0.f, 0.f, 0.f, 0.f};
            if ((unsigned)ii < 64u)
                v = *(const f32x4*)(xn + ((size_t)ic * HH + ii) * WW + cv * 4);
            float* dstp = xs + ic * XS_IC + row * XS_ROW;
            dstp[0 * XS_PAR + 2 * cv + 1] = v.x;   // col 4cv   (par0, h=2cv)
            dstp[1 * XS_PAR + 2 * cv + 1] = v.y;   // col 4cv+1 (par1, h=2cv)
            dstp[0 * XS_PAR + 2 * cv + 2] = v.z;   // col 4cv+2 (par0, h=2cv+1)
            dstp[1 * XS_PAR + 2 * cv + 2] = v.w;   // col 4cv+3 (par1, h=2cv+1)
        }
        // Col-halo zeros: par0 slot33 (col 64), par1 slot0 (col -1).
        int ic  = tid >> 3;
        int row = (tid >> 1) & 3;
        float* dstp = xs + ic * XS_IC + row * XS_ROW;
        if (tid & 1) dstp[1 * XS_PAR + 0]  = 0.f;
        else         dstp[0 * XS_PAR + 33] = 0.f;
    }

    if (pp == 0) packB<0>(w, (short8v*)Blds, tid);
    else         packB<1>(w, (short8v*)Blds, tid);
    __syncthreads();

    int wvv = __builtin_amdgcn_readfirstlane(tid >> 6);  // wave 0..3
    int grp = wvv;               // M-group 0..3
    int l   = tid & 63;

    int qA = grp * 16 + (l & 15);
    int rb = qA >> 5;                        // wave-uniform (0 or 1)
    int iA = i0 + rb;
    int pj = (iA + pp) & 1;                  // wave-uniform col parity
    int jA = 2 * (qA & 31) + pj;
    int icb = (l >> 4) * 8;

    // ---- Tap gather from LDS (values bit-identical to r17's global taps) ----
    int slotS = ((jA - 1) >> 1) + 1;         // side pair base (par 1-pj)
    int slotC = (jA >> 1) + 1;               // center (par pj)
    const float* xbase = xs + icb * XS_IC;

    float xt[8][9];
    #pragma unroll
    for (int a = 0; a < 8; ++a) {
        const float* pa = xbase + a * XS_IC;
        #pragma unroll
        for (int di = 0; di < 3; ++di) {
            const float* pr = pa + (rb + di) * XS_ROW;
            xt[a][di * 3 + 0] = pr[(1 - pj) * XS_PAR + slotS];
            xt[a][di * 3 + 2] = pr[(1 - pj) * XS_PAR + slotS + 1];
            xt[a][di * 3 + 1] = pr[pj * XS_PAR + slotC];
        }
    }

    const short8v* Bq = (const short8v*)Blds;
    f32x4 acc[4];
    if (pp == 0) aeg_gemm<0>(xt, Bq, acc, l);
    else         aeg_gemm<1>(xt, Bq, acc, l);

    // ---- Epilogue: coalesce C through LDS (B region dead after here) ----
    __syncthreads();                       // all waves done reading Blds
    float* cls = (float*)Blds;             // C-tile: cls[oc*65 + q], 16.6KB

    {
        int colc = l & 15;
        int rgrp = l >> 4;
        #pragma unroll
        for (int t = 0; t < 4; ++t) {
            int oc = t * 16 + colc;
            #pragma unroll
            for (int r = 0; r < 4; ++r) {
                int q = grp * 16 + rgrp * 4 + r;   // position 0..63 in block
                cls[oc * 65 + q] = acc[t][r];
            }
        }
    }
    __syncthreads();

    // Structured write-out: lane -> q, 64 lanes = one oc's 2-row stripe.
    #pragma unroll
    for (int v = 0; v < 16; ++v) {
        int flat = v * 256 + tid;          // 0..4095
        int oc   = flat >> 6;
        int q    = flat & 63;
        int i    = i0 + (q >> 5);
        int j    = 2 * (q & 31) + ((i + pp) & 1);
        out[(((size_t)n * C_OUT + oc) * HH + i) * WW + j] = cls[oc * 65 + q];
    }
}

extern "C" void kernel_launch(void* const* d_in, const int* in_sizes, int n_in,
                              void* d_out, int out_size, void* d_ws, size_t ws_size,
                              hipStream_t stream) {
    const float* x = (const float*)d_in[0];
    const float* w = (const float*)d_in[1];
    float* out = (float*)d_out;
    (void)d_ws; (void)ws_size;

    aeg_mfma<<<512, 256, 0, stream>>>(x, w, out);
}

// Round 20
// 17.076 us; speedup vs baseline: 1.1976x; 1.0904x over previous
//
#include <hip/hip_runtime.h>
#include <hip/hip_bf16.h>

#define C_IN  32
#define C_OUT 64
#define HH    64
#define WW    64

typedef __attribute__((ext_vector_type(8))) short short8v;
typedef __attribute__((ext_vector_type(4))) float f32x4;

static __device__ __forceinline__ unsigned short f2bf(float f) {
    unsigned u = __builtin_bit_cast(unsigned, f);
    unsigned r = (u + 0x7FFFu + ((u >> 16) & 1u)) >> 16;   // RNE
    return (unsigned short)r;
}

// x LDS geometry (r19, unchanged): per ic [row:4][par:2][slot:34], slot=h+1;
// per-ic stride 273 (==1 mod 4 -> 8-ic groups at bank offsets {0,8,16,24};
// 16-lane stride-1 reads -> <=2-way alias = free).
#define XS_IC   273
#define XS_ROW  68
#define XS_PAR  34

// ---------------------------------------------------------------------------
// FUSED W~ pack (r17/r19 math, hi-only). Covering thread tt (0..255) of
// parity P: oct = tt>>6, lane = tt&63, oc = oct*16+(lane&15),
// ic = (lane>>4)*8..+7. W~_k = Ew(k)*(w_k if (P+k) odd),
// Ew(k) = prod_{j>=k,(P+j) even} w_j.
// LDS: B16[P*2304 + (k*4+oct)*64 + lane] = short8 {8 ics' bf16 hi} (16B).
// ---------------------------------------------------------------------------
template<int P>
__device__ __forceinline__ void packB(const float* __restrict__ w,
                                      short8v* __restrict__ B16, int tt)
{
    int oct  = tt >> 6;
    int lane = tt & 63;
    int oc   = oct * 16 + (lane & 15);
    int icb  = (lane >> 4) * 8;

    float wv[72];
    const f32x4* src = (const f32x4*)(w + ((size_t)oc * C_IN + icb) * 9);
    #pragma unroll
    for (int i = 0; i < 18; ++i) {
        f32x4 v = src[i];
        wv[4 * i + 0] = v.x; wv[4 * i + 1] = v.y;
        wv[4 * i + 2] = v.z; wv[4 * i + 3] = v.w;
    }

    #pragma unroll
    for (int a = 0; a < 8; ++a) {
        float Ew = 1.f;
        #pragma unroll
        for (int k = 8; k >= 0; --k) {
            float wk = wv[9 * a + k];
            if (((P + k) & 1) == 0) { Ew *= wk; wv[9 * a + k] = Ew; }
            else                    { wv[9 * a + k] = wk * Ew; }
        }
    }

    #pragma unroll
    for (int k = 0; k < 9; ++k) {
        short8v vh;
        #pragma unroll
        for (int a = 0; a < 8; ++a)
            vh[a] = (short)f2bf(wv[9 * a + k]);
        B16[P * 2304 + (k * 4 + oct) * 64 + lane] = vh;
    }
}

// ---------------------------------------------------------------------------
// GEMM body — r17/r19 verified (A = X~, B = W~ hi, 2-term). UNCHANGED.
// C mapping (m89): row=(l>>4)*4+r -> position, col=l&15 -> oc.
// ---------------------------------------------------------------------------
template<int P>
__device__ __forceinline__ void aeg_gemm(
    float (&xt)[8][9], const short8v* __restrict__ Bq, f32x4 (&acc)[4], int l)
{
    #pragma unroll
    for (int a = 0; a < 8; ++a) {
        float Ox = 1.f;
        #pragma unroll
        for (int k = 8; k >= 0; --k) {
            if (((P + k) & 1) == 1) { Ox *= xt[a][k]; xt[a][k] = Ox; }
            else                    { xt[a][k] = xt[a][k] * Ox; }
        }
    }

    #pragma unroll
    for (int t = 0; t < 4; ++t) acc[t] = (f32x4){0.f, 0.f, 0.f, 0.f};

    #pragma unroll
    for (int k = 0; k < 9; ++k) {
        short8v ah, al;
        #pragma unroll
        for (int a = 0; a < 8; ++a) {
            float v  = xt[a][k];
            __hip_bfloat16 bh = __float2bfloat16(v);          // RNE
            float fh = __bfloat162float(bh);
            __hip_bfloat16 bl = __float2bfloat16(v - fh);
            ah[a] = (short)__builtin_bit_cast(unsigned short, bh);
            al[a] = (short)__builtin_bit_cast(unsigned short, bl);
        }
        #pragma unroll
        for (int t = 0; t < 4; ++t) {
            short8v bh = Bq[(k * 4 + t) * 64 + l];             // W~ hi only
            acc[t] = __builtin_amdgcn_mfma_f32_16x16x32_bf16(ah, bh, acc[t], 0, 0, 0);
            acc[t] = __builtin_amdgcn_mfma_f32_16x16x32_bf16(al, bh, acc[t], 0, 0, 0);
        }
    }
}

// ---------------------------------------------------------------------------
// Main kernel, DUAL-PARITY: block = 1 n x 2 rows x 64 cols x BOTH parities.
// 512 threads = 8 waves; waves 0-3 parity 0 (M-groups 0-3), waves 4-7
// parity 1. Grid 256 = 1 block/CU exactly (single generation). x-slab staged
// ONCE for both parities (halves stage work vs r19); epilogue assembles the
// full checkerboard tile in LDS -> complete-cache-line HBM writes (kills the
// 2x write amplification r13 measured). LDS: B 72KB + x 35KB = 107KB.
// ---------------------------------------------------------------------------
__global__ __launch_bounds__(512, 2) void aeg_mfma(
    const float* __restrict__ x, const float* __restrict__ w,
    float* __restrict__ out)
{
    __shared__ __attribute__((aligned(16))) unsigned short Blds[36864]; // 72KB (2 parities)
    __shared__ float xs[C_IN * XS_IC];                                  // 34.9KB

    int bid = blockIdx.x;
    int br  = bid & 31;          // row-block (0..31), 2 rows each
    int n   = bid >> 5;          // batch (0..7)
    int i0  = br * 2;
    int tid = threadIdx.x;

    // ---- Stage x slab: rows i0-1..i0+2, cols 0..63, all 32 ic (once) ----
    {
        const float* xn = x + (size_t)n * C_IN * HH * WW;
        #pragma unroll
        for (int c4 = 0; c4 < 4; ++c4) {
            int chunk = c4 * 512 + tid;      // 0..2047
            int ic  = chunk >> 6;
            int row = (chunk >> 4) & 3;
            int cv  = chunk & 15;
            int ii  = i0 - 1 + row;
            f32x4 v = (f32x4){0.f, 0.f, 0.f, 0.f};
            if ((unsigned)ii < 64u)
                v = *(const f32x4*)(xn + ((size_t)ic * HH + ii) * WW + cv * 4);
            float* dstp = xs + ic * XS_IC + row * XS_ROW;
            dstp[0 * XS_PAR + 2 * cv + 1] = v.x;
            dstp[1 * XS_PAR + 2 * cv + 1] = v.y;
            dstp[0 * XS_PAR + 2 * cv + 2] = v.z;
            dstp[1 * XS_PAR + 2 * cv + 2] = v.w;
        }
        if (tid < 256) {         // col-halo zeros (32ic x 4row x 2 halos)
            int ic  = tid >> 3;
            int row = (tid >> 1) & 3;
            float* dstp = xs + ic * XS_IC + row * XS_ROW;
            if (tid & 1) dstp[1 * XS_PAR + 0]  = 0.f;
            else         dstp[0 * XS_PAR + 33] = 0.f;
        }
    }

    // ---- Pack both parities' B (waves 0-3 -> P0, waves 4-7 -> P1) ----
    if (tid < 256) packB<0>(w, (short8v*)Blds, tid);
    else           packB<1>(w, (short8v*)Blds, tid - 256);
    __syncthreads();

    int wvv = __builtin_amdgcn_readfirstlane(tid >> 6);  // wave 0..7
    int pp  = wvv >> 2;          // parity (0..1)
    int grp = wvv & 3;           // M-group 0..3
    int l   = tid & 63;

    int qA = grp * 16 + (l & 15);
    int rb = qA >> 5;                        // wave-uniform (0 or 1)
    int iA = i0 + rb;
    int pj = (iA + pp) & 1;                  // wave-uniform col parity
    int jA = 2 * (qA & 31) + pj;
    int icb = (l >> 4) * 8;

    // ---- Tap gather from LDS (bit-identical values to r19) ----
    int slotS = ((jA - 1) >> 1) + 1;
    int slotC = (jA >> 1) + 1;
    const float* xbase = xs + icb * XS_IC;

    float xt[8][9];
    #pragma unroll
    for (int a = 0; a < 8; ++a) {
        const float* pa = xbase + a * XS_IC;
        #pragma unroll
        for (int di = 0; di < 3; ++di) {
            const float* pr = pa + (rb + di) * XS_ROW;
            xt[a][di * 3 + 0] = pr[(1 - pj) * XS_PAR + slotS];
            xt[a][di * 3 + 2] = pr[(1 - pj) * XS_PAR + slotS + 1];
            xt[a][di * 3 + 1] = pr[pj * XS_PAR + slotC];
        }
    }

    const short8v* Bq = (const short8v*)Blds + pp * 2304;
    f32x4 acc[4];
    if (pp == 0) aeg_gemm<0>(xt, Bq, acc, l);
    else         aeg_gemm<1>(xt, Bq, acc, l);

    // ---- Epilogue: assemble FULL tile (both parities) in LDS, store ----
    __syncthreads();                       // all B reads done
    float* cls = (float*)Blds;             // cls[oc*130 + pp*64 + q], 33.3KB

    {
        int colc = l & 15;
        int rgrp = l >> 4;
        #pragma unroll
        for (int t = 0; t < 4; ++t) {
            int oc = t * 16 + colc;
            #pragma unroll
            for (int r = 0; r < 4; ++r) {
                int q = grp * 16 + rgrp * 4 + r;   // position 0..63 in parity
                cls[oc * 130 + pp * 64 + q] = acc[t][r];
            }
        }
    }
    __syncthreads();

    // Full-line write-out: 8192 values, lane -> q within (oc, parity) stripe.
    #pragma unroll
    for (int v = 0; v < 16; ++v) {
        int flat = v * 512 + tid;          // 0..8191
        int oc   = flat >> 7;
        int rr   = flat & 127;
        int pq   = rr >> 6;                // parity
        int q    = rr & 63;
        int i    = i0 + (q >> 5);
        int j    = 2 * (q & 31) + ((i + pq) & 1);
        out[(((size_t)n * C_OUT + oc) * HH + i) * WW + j] = cls[oc * 130 + pq * 64 + q];
    }
}

extern "C" void kernel_launch(void* const* d_in, const int* in_sizes, int n_in,
                              void* d_out, int out_size, void* d_ws, size_t ws_size,
                              hipStream_t stream) {
    const float* x = (const float*)d_in[0];
    const float* w = (const float*)d_in[1];
    float* out = (float*)d_out;
    (void)d_ws; (void)ws_size;

    aeg_mfma<<<256, 512, 0, stream>>>(x, w, out);
}